// Round 6
// baseline (169.914 us; speedup 1.0000x reference)
//
#include <hip/hip_runtime.h>

// RSI replicating jax-CPU cumsum via XLA ReduceWindowRewriter(base_length=16):
//   pad e[0..NP) with trailing zeros to 8192; reshape [512,16]
//   level-0: each 16-tile scanned SEQUENTIALLY (naive small reduce_window,
//            acc = 0, then left-to-right RN adds)
//   tile sums (512) -> recursively same: [32,16] seq tiles -> sums (32) ->
//            [2,16] seq tiles -> sums (2) -> naive len-2 scan
//   unwind: each element gets ONE RN add of the finalized exclusive outer
//            offset (broadcast add), per level.
// Epilogue op-for-op IEEE f32 like the reference:
//   a = cs[o+w-1] - (o>=1 ? cs[o-1] : 0);  ag = a/w; al = b/w;
//   rs = (al!=0) ? ag/al : 0;  out = 1 - 1/(1+rs)
// (Environment proven IEEE, no fast-math: R2 (compiler ops) == R3 (raw asm)
//  bit-identical.)

constexpr int ROWS = 2048;
constexpr int COLS = 8192;
constexpr int NP   = COLS - 1;   // 8191 p-values; padded to 8192
constexpr int BT   = 256;

__global__ __launch_bounds__(BT, 1)
void rsi_rwr_kernel(const float* __restrict__ x,
                    const int* __restrict__ wsp,
                    float* __restrict__ out,
                    int outW)
{
    __shared__ float CG[8192], CL[8192];   // level-0 scan values -> final cumsum
    __shared__ float T0g[512], T0l[512];   // level-0 tile sums
    __shared__ float S1g[512], S1l[512];   // level-1 scan values (then finalized)
    __shared__ float T1g[32],  T1l[32];    // level-1 tile sums
    __shared__ float S2g[32],  S2l[32];    // level-2 scan values (then finalized)
    __shared__ float T2g[2],   T2l[2];     // level-2 tile sums
    __shared__ float S3g[2],   S3l[2];     // level-3 scan (len 2, naive)

    const int row = blockIdx.x;
    const int t   = threadIdx.x;
    const int wm1 = *wsp - 1;              // 13
    const float wf = (float)wm1;

    const float* __restrict__ xr = x + (size_t)row * COLS;

    // ---- phase A: elements + level-0 sequential 16-tile scans
    for (int b = t; b < 512; b += BT) {
        const float4* xv = reinterpret_cast<const float4*>(xr + 16 * b);
        float xe[17];
        {
            float4 v0 = xv[0], v1 = xv[1], v2 = xv[2], v3 = xv[3];
            xe[0]=v0.x;  xe[1]=v0.y;  xe[2]=v0.z;  xe[3]=v0.w;
            xe[4]=v1.x;  xe[5]=v1.y;  xe[6]=v1.z;  xe[7]=v1.w;
            xe[8]=v2.x;  xe[9]=v2.y;  xe[10]=v2.z; xe[11]=v2.w;
            xe[12]=v3.x; xe[13]=v3.y; xe[14]=v3.z; xe[15]=v3.w;
        }
        xe[16] = (b < 511) ? xr[16 * b + 16] : 0.f;   // unused for j==NP

        float cg = 0.f, cl = 0.f;
        for (int r = 0; r < 16; ++r) {
            const int j = 16 * b + r;
            float eg = 0.f, el = 0.f;
            if (j < NP) {
                const float prev = xe[r];
                const float nxt  = xe[r + 1];
                if (prev != 0.f) {
                    const float p = (nxt - prev) / prev;   // IEEE f32 div
                    eg = (p > 0.f) ?  p : 0.f;
                    el = (p < 0.f) ? -p : 0.f;
                }
            }
            cg = cg + eg;          // RN; trailing pad adds +0 (bit-neutral)
            cl = cl + el;
            CG[j] = cg;
            CL[j] = cl;
        }
        T0g[b] = cg; T0l[b] = cl;
    }
    __syncthreads();

    // ---- phase B1: level-1 sequential 16-tile scans over T0 (32 tiles)
    if (t < 32) {
        float cg = 0.f, cl = 0.f;
        for (int s = 0; s < 16; ++s) {
            cg = cg + T0g[16 * t + s];
            cl = cl + T0l[16 * t + s];
            S1g[16 * t + s] = cg;
            S1l[16 * t + s] = cl;
        }
        T1g[t] = cg; T1l[t] = cl;
    }
    __syncthreads();

    // ---- phase B2: level-2 sequential 16-tile scans over T1 (2 tiles)
    if (t < 2) {
        float cg = 0.f, cl = 0.f;
        for (int u = 0; u < 16; ++u) {
            cg = cg + T1g[16 * t + u];
            cl = cl + T1l[16 * t + u];
            S2g[16 * t + u] = cg;
            S2l[16 * t + u] = cl;
        }
        T2g[t] = cg; T2l[t] = cl;
    }
    __syncthreads();

    // ---- phase B3: level-3 naive scan of T2 (len 2 <= base)
    if (t == 0) {
        S3g[0] = T2g[0]; S3g[1] = T2g[0] + T2g[1];
        S3l[0] = T2l[0]; S3l[1] = T2l[0] + T2l[1];
    }
    __syncthreads();
    // finalize S2: tile d=1 gets exclusive offset S3[0]
    if (t >= 16 && t < 32) {
        const int k = t;                       // 16..31
        S2g[k] = S2g[k] + S3g[0];
        S2l[k] = S2l[k] + S3l[0];
    }
    __syncthreads();
    // finalize S1: tiles c>=1 get exclusive offset S2[c-1]
    for (int k = 16 + t; k < 512; k += BT) {
        const int c = k >> 4;
        S1g[k] = S1g[k] + S2g[c - 1];
        S1l[k] = S1l[k] + S2l[c - 1];
    }
    __syncthreads();

    // ---- phase C: element offsets: tiles b>=1 get exclusive offset S1[b-1]
    for (int b = t; b < 512; b += BT) {
        if (b >= 1) {
            const float og = S1g[b - 1], ol = S1l[b - 1];
            for (int r = 0; r < 16; ++r) {
                CG[16 * b + r] = CG[16 * b + r] + og;   // single RN add
                CL[16 * b + r] = CL[16 * b + r] + ol;
            }
        }
    }
    __syncthreads();

    // ---- phase D: epilogue, op-for-op IEEE f32
    float* __restrict__ outr = out + (size_t)row * outW;
    for (int o = t; o < outW; o += BT) {
        const float cg1 = (o >= 1) ? CG[o - 1] : 0.f;
        const float cl1 = (o >= 1) ? CL[o - 1] : 0.f;
        const float a  = CG[o + wm1 - 1] - cg1;
        const float bb = CL[o + wm1 - 1] - cl1;
        const float ag = a / wf;
        const float al = bb / wf;
        const float rs = (al != 0.f) ? (ag / al) : 0.f;
        outr[o] = 1.f - 1.f / (1.f + rs);
    }
}

extern "C" void kernel_launch(void* const* d_in, const int* in_sizes, int n_in,
                              void* d_out, int out_size, void* d_ws, size_t ws_size,
                              hipStream_t stream) {
    const float* x   = (const float*)d_in[0];
    const int*   wsp = (const int*)d_in[1];
    float*       out = (float*)d_out;

    const int outW = out_size / ROWS;   // 8179
    dim3 grid(ROWS);                    // one block per row
    dim3 block(BT);
    rsi_rwr_kernel<<<grid, block, 0, stream>>>(x, wsp, out, outW);
}